// Round 3
// baseline (560.570 us; speedup 1.0000x reference)
//
#include <hip/hip_runtime.h>
#include <math.h>

// Problem sizes
constexpr int NPTS = 8192;
constexpr int DIM  = 512;
constexpr int KC   = 8;    // clusters
constexpr int NNB  = 5;    // neighbors

// Output layout (floats)
constexpr int OFF_ENC    = 0;
constexpr int OFF_ASSIGN = NPTS * 32;                 // 262144
constexpr int OFF_KNN    = OFF_ASSIGN + NPTS * KC;    // 327680
constexpr int OFF_STATS  = OFF_KNN + NPTS * NNB;      // 368640
constexpr int OFF_LOSS   = OFF_STATS + NPTS * 3;      // 393216 (loss, intra, inter)

// Workspace layout (float offsets)
constexpr int WS_CNORM = 0;            // 8
constexpr int WS_INTER = 8;            // 1
constexpr int WS_XX    = 16;           // 8192 row norms
constexpr int WS_INTRA = 16 + NPTS;    // 512 block partials
constexpr int WS_CAND  = 16 + NPTS + 512; // float2[NPTS][40] candidates (key, idx)
constexpr size_t XB_OFF = 4u << 20;    // byte offset of bf16 copy of x (8 MB)

typedef short bf16x8 __attribute__((ext_vector_type(8)));
typedef float f32x16 __attribute__((ext_vector_type(16)));

__device__ __forceinline__ float waveAllSum(float v) {
#pragma unroll
  for (int m = 1; m < 64; m <<= 1) v += __shfl_xor(v, m);
  return v;
}
__device__ __forceinline__ float waveAllMax(float v) {
#pragma unroll
  for (int m = 1; m < 64; m <<= 1) v = fmaxf(v, __shfl_xor(v, m));
  return v;
}

__device__ __forceinline__ unsigned short f2bf(float f) {
  unsigned u = __float_as_uint(f);
  unsigned r = (u + 0x7FFFu + ((u >> 16) & 1u)) >> 16;  // RNE
  return (unsigned short)r;
}

// async global(16B/lane) -> LDS, linear dest (wave-uniform base + lane*16)
__device__ __forceinline__ void gload16(const void* g, void* lds) {
  __builtin_amdgcn_global_load_lds(
      (const __attribute__((address_space(1))) unsigned int*)(unsigned long long)g,
      (__attribute__((address_space(3))) unsigned int*)(unsigned)(unsigned long long)lds,
      16, 0, 0);
}

// ---------------- k_init: center norms + inter-cluster distance ----------------
__global__ void k_init(const float* __restrict__ cc, float* __restrict__ ws) {
  int t = threadIdx.x;
  if (t < KC) {
    float s = 0.f;
    for (int j = 0; j < DIM; j++) { float v = cc[t * DIM + j]; s = fmaf(v, v, s); }
    ws[WS_CNORM + t] = s;
  }
  __syncthreads();
  int i = t >> 3, j = t & 7;
  float dot = 0.f;
  for (int u = 0; u < DIM; u++) dot = fmaf(cc[i * DIM + u], cc[j * DIM + u], dot);
  float d2 = ws[WS_CNORM + i] + ws[WS_CNORM + j] - 2.f * dot;
  float d = d2 > 0.f ? sqrtf(d2) : 0.f;
  float v = (i != j) ? d : 0.f;
  v = waveAllSum(v);
  if (t == 0) ws[WS_INTER] = v / 56.f;
}

// ---------------- k_stats: row stats + soft assignment + intra partials --------
__global__ __launch_bounds__(256) void k_stats(
    const float* __restrict__ x, const float* __restrict__ cc,
    const float* __restrict__ temp, const float* __restrict__ cw,
    float* __restrict__ out, float* __restrict__ ws) {
  __shared__ __align__(16) float Cs[KC * DIM];
  __shared__ float cns[KC], cwS[KC];
  __shared__ float intraS[4];
  int tid = threadIdx.x;
  for (int i = tid * 4; i < KC * DIM; i += 1024)
    *(float4*)&Cs[i] = *(const float4*)&cc[i];
  if (tid < KC) { cns[tid] = ws[WS_CNORM + tid]; cwS[tid] = cw[tid]; }
  __syncthreads();
  float T = temp[0];
  int w = tid >> 6, l = tid & 63;
  float intra_acc = 0.f;
  for (int q = 0; q < 4; q++) {
    int row = blockIdx.x * 16 + w * 4 + q;
    float4 v0 = *(const float4*)&x[row * DIM + l * 4];
    float4 v1 = *(const float4*)&x[row * DIM + 256 + l * 4];
    float xv[8] = {v0.x, v0.y, v0.z, v0.w, v1.x, v1.y, v1.z, v1.w};
    float s1 = 0.f, s2 = 0.f, mx = -3e38f;
#pragma unroll
    for (int u = 0; u < 8; u++) { s1 += xv[u]; s2 = fmaf(xv[u], xv[u], s2); mx = fmaxf(mx, xv[u]); }
    s1 = waveAllSum(s1); s2 = waveAllSum(s2); mx = waveAllMax(mx);
    float e = 0.f, ex = 0.f;
#pragma unroll
    for (int u = 0; u < 8; u++) { float p = expf(xv[u] - mx); e += p; ex = fmaf(xv[u], p, ex); }
    e = waveAllSum(e); ex = waveAllSum(ex);
    float dk[KC];
#pragma unroll
    for (int k = 0; k < KC; k++) {
      float4 c0 = *(const float4*)&Cs[k * DIM + l * 4];
      float4 c1 = *(const float4*)&Cs[k * DIM + 256 + l * 4];
      float d = v0.x * c0.x + v0.y * c0.y + v0.z * c0.z + v0.w * c0.w
              + v1.x * c1.x + v1.y * c1.y + v1.z * c1.z + v1.w * c1.w;
      dk[k] = waveAllSum(d);
    }
    float mu = s1 / 512.f;
    float var = (s2 - 512.f * mu * mu) / 511.f;
    if (var < 0.f) var = 0.f;
    float sd = sqrtf(var) + 1e-8f;
    float lse = mx + logf(e);
    float ent = lse - ex / e;
    float dcv[KC], am = -3e38f;
#pragma unroll
    for (int k = 0; k < KC; k++) {
      float d2 = s2 + cns[k] - 2.f * dk[k];
      dcv[k] = d2 > 0.f ? sqrtf(d2) : 0.f;
      am = fmaxf(am, -dcv[k] / T);
    }
    float psum = 0.f, pv[KC];
#pragma unroll
    for (int k = 0; k < KC; k++) { pv[k] = expf(-dcv[k] / T - am); psum += pv[k]; }
    float il = 0.f, asg[KC];
#pragma unroll
    for (int k = 0; k < KC; k++) { asg[k] = pv[k] / psum * cwS[k]; il = fmaf(dcv[k], asg[k], il); }
    intra_acc += il;
    if (l == 0) {
      ws[WS_XX + row] = s2;
      out[OFF_STATS + row * 3 + 0] = mu;
      out[OFF_STATS + row * 3 + 1] = sd;
      out[OFF_STATS + row * 3 + 2] = ent;
#pragma unroll
      for (int k = 0; k < KC; k++) out[OFF_ASSIGN + row * KC + k] = asg[k];
    }
  }
  if (l == 0) intraS[w] = intra_acc;
  __syncthreads();
  if (tid == 0)
    ws[WS_INTRA + blockIdx.x] = intraS[0] + intraS[1] + intraS[2] + intraS[3];
}

// ---------------- k_final: scalar loss outputs ----------------
__global__ void k_final(float* __restrict__ out, const float* __restrict__ ws) {
  __shared__ float ps[4];
  int t = threadIdx.x;
  float v = ws[WS_INTRA + t] + ws[WS_INTRA + t + 256];
  v = waveAllSum(v);
  if ((t & 63) == 0) ps[t >> 6] = v;
  __syncthreads();
  if (t == 0) {
    float intra = (ps[0] + ps[1] + ps[2] + ps[3]) / (8192.f * 8.f);
    float inter = ws[WS_INTER];
    out[OFF_LOSS + 0] = intra - 0.1f * inter;
    out[OFF_LOSS + 1] = intra;
    out[OFF_LOSS + 2] = inter;
  }
}

// ---------------- k_cvt: x f32 -> bf16 (RNE) ----------------
__global__ __launch_bounds__(256) void k_cvt(const float* __restrict__ x,
                                             unsigned short* __restrict__ xb) {
  int i = (blockIdx.x * 256 + threadIdx.x) * 8;
  float4 v0 = *(const float4*)&x[i];
  float4 v1 = *(const float4*)&x[i + 4];
  bf16x8 o;
  o[0] = (short)f2bf(v0.x); o[1] = (short)f2bf(v0.y);
  o[2] = (short)f2bf(v0.z); o[3] = (short)f2bf(v0.w);
  o[4] = (short)f2bf(v1.x); o[5] = (short)f2bf(v1.y);
  o[6] = (short)f2bf(v1.z); o[7] = (short)f2bf(v1.w);
  *(bf16x8*)&xb[i] = o;
}

// ---------------- k_gemm2: swapped-operand MFMA + 2-phase pipeline -----------
// grid (64, 8): 128-row tile x 1024-col chunk (8 col-tiles of 128).
// 4 waves as (wr: col-half, wc: row-half); wave tile cols 64 x rows 64 =
// 2x2 frags of mfma_f32_32x32x16_bf16 with OPERANDS SWAPPED:
//   acc[mf][nf] = mfma(colfrag[mf], rowfrag[nf]) -> D[col in regs][row in lane]
// so top-5 per row is lane-local. BK=64, double-buffered LDS, one barrier/step.

// top-5 insert (strict <, earlier/lower idx wins ties)
#define INS5(P, KEY, IDX)                                                        \
  { float a_ = (KEY); int b_ = (IDX);                                            \
    if (a_ < k##P##0) { float t_=k##P##0; k##P##0=a_; a_=t_; int u_=i##P##0; i##P##0=b_; b_=u_; } \
    if (a_ < k##P##1) { float t_=k##P##1; k##P##1=a_; a_=t_; int u_=i##P##1; i##P##1=b_; b_=u_; } \
    if (a_ < k##P##2) { float t_=k##P##2; k##P##2=a_; a_=t_; int u_=i##P##2; i##P##2=b_; b_=u_; } \
    if (a_ < k##P##3) { float t_=k##P##3; k##P##3=a_; a_=t_; int u_=i##P##3; i##P##3=b_; b_=u_; } \
    if (a_ < k##P##4) { float t_=k##P##4; k##P##4=a_; a_=t_; int u_=i##P##4; i##P##4=b_; b_=u_; } \
    float t5_ = k##P##4 + 8e-6f; t2##P = t5_ * t5_; }

#define PROC(P, DOT, XC, COL, ROW, XR, NROW)                                     \
  { float d2_ = (XR) + (XC) - 2.0f * (DOT);                                      \
    if (d2_ < t2##P) {                                                           \
      float d_ = sqrtf(fmaxf(d2_, 0.0f));                                        \
      int c_ = (COL);                                                            \
      if (c_ != (ROW)) {                                                         \
        float key_ = fmaf(1e-6f, (NROW)[c_], d_);                                \
        if (key_ < k##P##4) { INS5(P, key_, c_) }                                \
      } } }

// stage one BK=64 K-slice of the col-tile (16KB) + row-tile (16KB) into buf.
// per-lane source pre-swizzled (sg = slot^row) so linear LDS dest ends up
// XOR-swizzled; read side applies the same XOR.
#define STAGE(STEP, BUF) {                                                       \
    const int ct_ = (STEP) >> 3;                                                 \
    const size_t kb_ = (size_t)(((STEP) & 7) << 6) + sg * 8;                     \
    const int cb_ = colbase + ct_ * 128 + w * 32 + srow;                         \
    const int rb_ = rowbase + w * 32 + srow;                                     \
    char* db_ = SMEM[BUF] + w * 4096;                                            \
    gload16(xb + (size_t)(cb_ + 0) * DIM + kb_, db_ + 0);                        \
    gload16(xb + (size_t)(rb_ + 0) * DIM + kb_, db_ + 16384);                    \
    gload16(xb + (size_t)(cb_ + 8) * DIM + kb_, db_ + 1024);                     \
    gload16(xb + (size_t)(rb_ + 8) * DIM + kb_, db_ + 17408);                    \
    gload16(xb + (size_t)(cb_ + 16) * DIM + kb_, db_ + 2048);                    \
    gload16(xb + (size_t)(rb_ + 16) * DIM + kb_, db_ + 18432);                   \
    gload16(xb + (size_t)(cb_ + 24) * DIM + kb_, db_ + 3072);                    \
    gload16(xb + (size_t)(rb_ + 24) * DIM + kb_, db_ + 19456);                   \
  }

__global__ __launch_bounds__(256) void k_gemm2(
    const unsigned short* __restrict__ xb, const float* __restrict__ noise,
    float* __restrict__ ws) {
  __shared__ __align__(16) char SMEM[2][32768];  // [buf][cols 16K | rows 16K]
  const int tid = threadIdx.x;
  const int l = tid & 63, w = tid >> 6;
  const int wr = w >> 1, wc = w & 1;       // wr: col-half, wc: row-half
  const int rowbase = blockIdx.x * 128;
  const int colbase = blockIdx.y * 1024;
  const float* xxg = ws + WS_XX;
  float2* candp = (float2*)(ws + WS_CAND);

  const int l7 = l & 7, lh = l >> 5, l31 = l & 31;
  const int srow = l >> 3;
  const int sg = (l & 7) ^ srow;

  // my two rows (nf=0 / nf=1)
  const int rowA = rowbase + wc * 64 + l31;
  const int rowB = rowA + 32;
  const float xxrA = xxg[rowA], xxrB = xxg[rowB];
  const float* nrowA = noise + (size_t)rowA * NPTS;
  const float* nrowB = noise + (size_t)rowB * NPTS;

  // fragment read byte-bases within a buffer
  const int cAb0 = (wr * 64 + l31) << 7;             // col tile, mf=0
  const int cAb1 = cAb0 + (32 << 7);                 // mf=1
  const int rBb0 = 16384 + ((wc * 64 + l31) << 7);   // row tile, nf=0
  const int rBb1 = rBb0 + (32 << 7);                 // nf=1

  float ka0=3e38f,ka1=3e38f,ka2=3e38f,ka3=3e38f,ka4=3e38f;
  float kb0=3e38f,kb1=3e38f,kb2=3e38f,kb3=3e38f,kb4=3e38f;
  int   ia0=-1,ia1=-1,ia2=-1,ia3=-1,ia4=-1;
  int   ib0=-1,ib1=-1,ib2=-1,ib3=-1,ib4=-1;
  float t2a = 3e38f, t2b = 3e38f;

  f32x16 a00, a01, a10, a11;
#pragma unroll
  for (int r = 0; r < 16; r++) { a00[r]=0.f; a01[r]=0.f; a10[r]=0.f; a11[r]=0.f; }

  STAGE(0, 0)
  __syncthreads();  // drain vmcnt(0): buf0 ready

  for (int step = 0; step < 64; ++step) {
    const int cur = step & 1;
    if (step < 63) STAGE(step + 1, cur ^ 1)
    const char* Bp = SMEM[cur];
#pragma unroll
    for (int kk = 0; kk < 4; kk++) {
      const int offk = ((lh + 2 * kk) ^ l7) << 4;
      bf16x8 c0 = *(const bf16x8*)(Bp + cAb0 + offk);
      bf16x8 c1 = *(const bf16x8*)(Bp + cAb1 + offk);
      bf16x8 r0 = *(const bf16x8*)(Bp + rBb0 + offk);
      bf16x8 r1 = *(const bf16x8*)(Bp + rBb1 + offk);
      a00 = __builtin_amdgcn_mfma_f32_32x32x16_bf16(c0, r0, a00, 0, 0, 0);
      a01 = __builtin_amdgcn_mfma_f32_32x32x16_bf16(c0, r1, a01, 0, 0, 0);
      a10 = __builtin_amdgcn_mfma_f32_32x32x16_bf16(c1, r0, a10, 0, 0, 0);
      a11 = __builtin_amdgcn_mfma_f32_32x32x16_bf16(c1, r1, a11, 0, 0, 0);
    }
    if ((step & 7) == 7) {  // ct finished: register-local epilogue
      const int ct = step >> 3;
      const int colt = colbase + ct * 128 + wr * 64;
      float xq0[16], xq1[16];
#pragma unroll
      for (int g = 0; g < 4; g++) {
        float4 t0 = *(const float4*)&xxg[colt + 4 * lh + 8 * g];
        float4 t1 = *(const float4*)&xxg[colt + 32 + 4 * lh + 8 * g];
        xq0[4*g+0]=t0.x; xq0[4*g+1]=t0.y; xq0[4*g+2]=t0.z; xq0[4*g+3]=t0.w;
        xq1[4*g+0]=t1.x; xq1[4*g+1]=t1.y; xq1[4*g+2]=t1.z; xq1[4*g+3]=t1.w;
      }
#pragma unroll
      for (int r = 0; r < 16; r++) {
        const int cOff = (r & 3) + 8 * (r >> 2) + 4 * lh;
        PROC(a, a00[r], xq0[r], colt + cOff,      rowA, xxrA, nrowA)
        PROC(b, a01[r], xq0[r], colt + cOff,      rowB, xxrB, nrowB)
        PROC(a, a10[r], xq1[r], colt + 32 + cOff, rowA, xxrA, nrowA)
        PROC(b, a11[r], xq1[r], colt + 32 + cOff, rowB, xxrB, nrowB)
      }
#pragma unroll
      for (int r = 0; r < 16; r++) { a00[r]=0.f; a01[r]=0.f; a10[r]=0.f; a11[r]=0.f; }
    }
    __syncthreads();  // drains next-step stage; protects buf swap
  }

  // ---- lane^32 merge: partner lane holds same rows, other 32 cols ----
  float MA[5], MB_[5]; int JA[5], JB_[5];
  {
    float m0=ka0,m1=ka1,m2=ka2,m3=ka3,m4=ka4;
    int   n0=ia0,n1=ia1,n2=ia2,n3=ia3,n4=ia4;
#pragma unroll
    for (int s = 0; s < 5; s++) {
      float ok = __shfl_xor(m0, 32); int oi = __shfl_xor(n0, 32);
      bool take = (m0 < ok) || (m0 == ok && (unsigned)n0 <= (unsigned)oi);
      MA[s] = take ? m0 : ok; JA[s] = take ? n0 : oi;
      if (take) { m0=m1;n0=n1; m1=m2;n1=n2; m2=m3;n2=n3; m3=m4;n3=n4; m4=3e38f;n4=-1; }
    }
  }
  {
    float m0=kb0,m1=kb1,m2=kb2,m3=kb3,m4=kb4;
    int   n0=ib0,n1=ib1,n2=ib2,n3=ib3,n4=ib4;
#pragma unroll
    for (int s = 0; s < 5; s++) {
      float ok = __shfl_xor(m0, 32); int oi = __shfl_xor(n0, 32);
      bool take = (m0 < ok) || (m0 == ok && (unsigned)n0 <= (unsigned)oi);
      MB_[s] = take ? m0 : ok; JB_[s] = take ? n0 : oi;
      if (take) { m0=m1;n0=n1; m1=m2;n1=n2; m2=m3;n2=n3; m3=m4;n3=n4; m4=3e38f;n4=-1; }
    }
  }

  // ---- cross-wave (wr pair) merge via LDS (staging bufs now free) ----
  float2* mb = (float2*)SMEM;  // [128 local rows][5]
  if (wr == 1 && lh == 0) {
    const int ra5 = (wc * 64 + l31) * 5, rb5 = (wc * 64 + 32 + l31) * 5;
#pragma unroll
    for (int s = 0; s < 5; s++) {
      mb[ra5 + s] = make_float2(MA[s],  __int_as_float(JA[s]));
      mb[rb5 + s] = make_float2(MB_[s], __int_as_float(JB_[s]));
    }
  }
  __syncthreads();
  if (wr == 0 && lh == 0) {
    // list a (rowA)
    {
      float p[5]; int q[5];
      const int r5 = (wc * 64 + l31) * 5;
#pragma unroll
      for (int s = 0; s < 5; s++) { float2 c = mb[r5 + s]; p[s] = c.x; q[s] = __float_as_int(c.y); }
      float m[5]; int j[5];
#pragma unroll
      for (int s = 0; s < 5; s++) { m[s] = MA[s]; j[s] = JA[s]; }
      const size_t base = (size_t)rowA * 40 + blockIdx.y * 5;
#pragma unroll
      for (int s = 0; s < 5; s++) {
        bool take = (m[0] < p[0]) || (m[0] == p[0] && (unsigned)j[0] < (unsigned)q[0]);
        float wk = take ? m[0] : p[0]; int wi = take ? j[0] : q[0];
        candp[base + s] = make_float2(wk, __int_as_float(wi));
        if (take) { m[0]=m[1];j[0]=j[1]; m[1]=m[2];j[1]=j[2]; m[2]=m[3];j[2]=j[3]; m[3]=m[4];j[3]=j[4]; m[4]=3e38f; }
        else      { p[0]=p[1];q[0]=q[1]; p[1]=p[2];q[1]=q[2]; p[2]=p[3];q[2]=q[3]; p[3]=p[4];q[3]=q[4]; p[4]=3e38f; }
      }
    }
    // list b (rowB)
    {
      float p[5]; int q[5];
      const int r5 = (wc * 64 + 32 + l31) * 5;
#pragma unroll
      for (int s = 0; s < 5; s++) { float2 c = mb[r5 + s]; p[s] = c.x; q[s] = __float_as_int(c.y); }
      float m[5]; int j[5];
#pragma unroll
      for (int s = 0; s < 5; s++) { m[s] = MB_[s]; j[s] = JB_[s]; }
      const size_t base = (size_t)rowB * 40 + blockIdx.y * 5;
#pragma unroll
      for (int s = 0; s < 5; s++) {
        bool take = (m[0] < p[0]) || (m[0] == p[0] && (unsigned)j[0] < (unsigned)q[0]);
        float wk = take ? m[0] : p[0]; int wi = take ? j[0] : q[0];
        candp[base + s] = make_float2(wk, __int_as_float(wi));
        if (take) { m[0]=m[1];j[0]=j[1]; m[1]=m[2];j[1]=j[2]; m[2]=m[3];j[2]=j[3]; m[3]=m[4];j[3]=j[4]; m[4]=3e38f; }
        else      { p[0]=p[1];q[0]=q[1]; p[1]=p[2];q[1]=q[2]; p[2]=p[3];q[2]=q[3]; p[3]=p[4];q[3]=q[4]; p[4]=3e38f; }
      }
    }
  }
}

// ---------------- k_gemm (fallback, fp32 VALU): unchanged ----------------
__global__ __launch_bounds__(256, 2) void k_gemm(
    const float* __restrict__ x, const float* __restrict__ noise,
    float* __restrict__ ws) {
  __shared__ __align__(16) float As[16][132];
  __shared__ __align__(16) float Bs[16][132];
  __shared__ float xxc[1024];
  const int tid = threadIdx.x;
  const int tx = tid & 7, ty = tid >> 3;
  const int rowbase = blockIdx.x * 128;
  const int colbase = blockIdx.y * 1024;
  const float* xxg = ws + WS_XX;

  for (int i = tid; i < 1024; i += 256) xxc[i] = xxg[colbase + i];
  float xxr[4];
#pragma unroll
  for (int r = 0; r < 4; r++) xxr[r] = xxg[rowbase + ty * 4 + r];

  float k5[4][5]; int i5[4][5];
#pragma unroll
  for (int r = 0; r < 4; r++)
#pragma unroll
    for (int s = 0; s < 5; s++) { k5[r][s] = 3e38f; i5[r][s] = -1; }

  const int rlo = tid >> 2, kq = tid & 3;

  for (int ct = 0; ct < 8; ct++) {
    const int colt = colbase + ct * 128;
    float acc[4][16];
#pragma unroll
    for (int r = 0; r < 4; r++)
#pragma unroll
      for (int c = 0; c < 16; c++) acc[r][c] = 0.f;

    for (int kk = 0; kk < 512; kk += 16) {
      __syncthreads();
      float4 a0 = *(const float4*)&x[(rowbase + rlo) * DIM + kk + kq * 4];
      float4 a1 = *(const float4*)&x[(rowbase + rlo + 64) * DIM + kk + kq * 4];
      float4 b0 = *(const float4*)&x[(colt + rlo) * DIM + kk + kq * 4];
      float4 b1 = *(const float4*)&x[(colt + rlo + 64) * DIM + kk + kq * 4];
      As[kq * 4 + 0][rlo] = a0.x; As[kq * 4 + 1][rlo] = a0.y;
      As[kq * 4 + 2][rlo] = a0.z; As[kq * 4 + 3][rlo] = a0.w;
      As[kq * 4 + 0][rlo + 64] = a1.x; As[kq * 4 + 1][rlo + 64] = a1.y;
      As[kq * 4 + 2][rlo + 64] = a1.z; As[kq * 4 + 3][rlo + 64] = a1.w;
      Bs[kq * 4 + 0][rlo] = b0.x; Bs[kq * 4 + 1][rlo] = b0.y;
      Bs[kq * 4 + 2][rlo] = b0.z; Bs[kq * 4 + 3][rlo] = b0.w;
      Bs[kq * 4 + 0][rlo + 64] = b1.x; Bs[kq * 4 + 1][rlo + 64] = b1.y;
      Bs[kq * 4 + 2][rlo + 64] = b1.z; Bs[kq * 4 + 3][rlo + 64] = b1.w;
      __syncthreads();
#pragma unroll
      for (int k = 0; k < 16; k++) {
        float4 av = *(const float4*)&As[k][ty * 4];
        float a_[4] = {av.x, av.y, av.z, av.w};
#pragma unroll
        for (int j = 0; j < 4; j++) {
          float4 bv = *(const float4*)&Bs[k][tx * 4 + j * 32];
          float b_[4] = {bv.x, bv.y, bv.z, bv.w};
#pragma unroll
          for (int rr = 0; rr < 4; rr++)
#pragma unroll
            for (int uu = 0; uu < 4; uu++)
              acc[rr][j * 4 + uu] = fmaf(a_[rr], b_[uu], acc[rr][j * 4 + uu]);
        }
      }
    }
#pragma unroll
    for (int r = 0; r < 4; r++) {
      const int row = rowbase + ty * 4 + r;
#pragma unroll
      for (int j = 0; j < 4; j++) {
        const int cl = tx * 4 + j * 32;
        const int col = colt + cl;
        const float4 nz = *(const float4*)&noise[(size_t)row * NPTS + col];
        float nzv[4] = {nz.x, nz.y, nz.z, nz.w};
#pragma unroll
        for (int u = 0; u < 4; u++) {
          float d2 = xxr[r] + xxc[ct * 128 + cl + u] - 2.f * acc[r][j * 4 + u];
          float d = d2 > 0.f ? sqrtf(d2) : 0.f;
          float key = d + 1e-6f * nzv[u];
          int c = col + u;
          if (c != row && key < k5[r][4]) {
            float a = key; int b = c;
#pragma unroll
            for (int s = 0; s < 5; s++) {
              if (a < k5[r][s]) {
                float tf = k5[r][s]; k5[r][s] = a; a = tf;
                int ti = i5[r][s]; i5[r][s] = b; b = ti;
              }
            }
          }
        }
      }
    }
  }

#pragma unroll
  for (int r = 0; r < 4; r++) {
    const int row = rowbase + ty * 4 + r;
    float lk[5]; int li[5];
#pragma unroll
    for (int s = 0; s < 5; s++) { lk[s] = k5[r][s]; li[s] = i5[r][s]; }
#pragma unroll
    for (int s = 0; s < 5; s++) {
      float wk = lk[0]; int wi = li[0];
#pragma unroll
      for (int m = 1; m < 8; m <<= 1) {
        float k2 = __shfl_xor(wk, m); int i2 = __shfl_xor(wi, m);
        if (k2 < wk || (k2 == wk && (unsigned)i2 < (unsigned)wi)) { wk = k2; wi = i2; }
      }
      if (li[0] == wi && lk[0] == wk) {
        lk[0] = lk[1]; li[0] = li[1];
        lk[1] = lk[2]; li[1] = li[2];
        lk[2] = lk[3]; li[2] = li[3];
        lk[3] = lk[4]; li[3] = li[4];
        lk[4] = 3e38f; li[4] = -1;
      }
      if (tx == 0) {
        float2* cand = (float2*)(ws + WS_CAND);
        cand[(size_t)row * 40 + blockIdx.y * 5 + s] = make_float2(wk, __int_as_float(wi));
      }
    }
  }
}

// ---------------- k_merge: final top-5 + feats + MLP ----------------
__global__ __launch_bounds__(256) void k_merge(
    const float* __restrict__ noise, const float* __restrict__ w1,
    const float* __restrict__ b1, const float* __restrict__ w2,
    const float* __restrict__ b2, float* __restrict__ out,
    const float* __restrict__ ws) {
  __shared__ float w1s[16 * 64];
  __shared__ float b1s[64];
  __shared__ float w2s[64 * 32];
  __shared__ float b2s[32];
  __shared__ float featsS[4][16];
  __shared__ float hS[4][64];
  int tid = threadIdx.x;
  for (int i = tid; i < 1024; i += 256) w1s[i] = w1[i];
  for (int i = tid; i < 2048; i += 256) w2s[i] = w2[i];
  if (tid < 64) b1s[tid] = b1[tid];
  if (tid < 32) b2s[tid] = b2[tid];
  __syncthreads();
  int w = tid >> 6, l = tid & 63;
  const float2* cand = (const float2*)(ws + WS_CAND);
  for (int q = 0; q < 8; q++) {
    int row = blockIdx.x * 32 + w * 8 + q;
    float mk = 3e38f; int mi = -1;
    if (l < 40) {
      float2 c = cand[(size_t)row * 40 + l];
      mk = c.x; mi = __float_as_int(c.y);
    }
#pragma unroll
    for (int s = 0; s < 5; s++) {
      float wk = mk; int wi = mi;
#pragma unroll
      for (int m = 1; m < 64; m <<= 1) {
        float k2 = __shfl_xor(wk, m); int i2 = __shfl_xor(wi, m);
        if (k2 < wk || (k2 == wk && (unsigned)i2 < (unsigned)wi)) { wk = k2; wi = i2; }
      }
      if (mi == wi && mk == wk) mk = 3e38f;  // remove winner from my slot
      if (l == s) {
        float nv = noise[(size_t)row * NPTS + wi];
        float dclean = wk - 1e-6f * nv;
        out[OFF_KNN + row * NNB + s] = dclean;
        featsS[w][8 + s] = dclean;
      }
    }
    if (l < 8) featsS[w][l] = out[OFF_ASSIGN + row * KC + l];
    if (l >= 13 && l < 16) featsS[w][l] = out[OFF_STATS + row * 3 + (l - 13)];
    __syncthreads();
    float h = b1s[l];
#pragma unroll
    for (int i = 0; i < 16; i++) h = fmaf(featsS[w][i], w1s[i * 64 + l], h);
    hS[w][l] = fmaxf(h, 0.f);
    __syncthreads();
    if (l < 32) {
      float e = b2s[l];
#pragma unroll
      for (int i = 0; i < 64; i++) e = fmaf(hS[w][i], w2s[i * 32 + l], e);
      out[OFF_ENC + row * 32 + l] = e;
    }
    __syncthreads();
  }
}

extern "C" void kernel_launch(void* const* d_in, const int* in_sizes, int n_in,
                              void* d_out, int out_size, void* d_ws, size_t ws_size,
                              hipStream_t stream) {
  const float* x     = (const float*)d_in[0];
  const float* noise = (const float*)d_in[1];
  const float* cc    = (const float*)d_in[2];
  const float* w1    = (const float*)d_in[3];
  const float* b1    = (const float*)d_in[4];
  const float* w2    = (const float*)d_in[5];
  const float* b2    = (const float*)d_in[6];
  const float* temp  = (const float*)d_in[7];
  const float* cw    = (const float*)d_in[8];
  float* out = (float*)d_out;
  float* ws  = (float*)d_ws;

  const size_t need = XB_OFF + (size_t)NPTS * DIM * 2;  // 12.6 MB
  const bool fast = ws_size >= need;

  hipLaunchKernelGGL(k_init,  dim3(1),   dim3(64),  0, stream, cc, ws);
  hipLaunchKernelGGL(k_stats, dim3(512), dim3(256), 0, stream, x, cc, temp, cw, out, ws);
  hipLaunchKernelGGL(k_final, dim3(1),   dim3(256), 0, stream, out, ws);
  if (fast) {
    unsigned short* xb = (unsigned short*)((char*)d_ws + XB_OFF);
    hipLaunchKernelGGL(k_cvt,   dim3(2048),  dim3(256), 0, stream, x, xb);
    hipLaunchKernelGGL(k_gemm2, dim3(64, 8), dim3(256), 0, stream, xb, noise, ws);
  } else {
    hipLaunchKernelGGL(k_gemm,  dim3(64, 8), dim3(256), 0, stream, x, noise, ws);
  }
  hipLaunchKernelGGL(k_merge, dim3(256), dim3(256), 0, stream, noise, w1, b1, w2, b2, out, ws);
}

// Round 4
// 347.177 us; speedup vs baseline: 1.6147x; 1.6147x over previous
//
#include <hip/hip_runtime.h>
#include <math.h>

// Problem sizes
constexpr int NPTS = 8192;
constexpr int DIM  = 512;
constexpr int KC   = 8;    // clusters
constexpr int NNB  = 5;    // neighbors

// Output layout (floats)
constexpr int OFF_ENC    = 0;
constexpr int OFF_ASSIGN = NPTS * 32;                 // 262144
constexpr int OFF_KNN    = OFF_ASSIGN + NPTS * KC;    // 327680
constexpr int OFF_STATS  = OFF_KNN + NPTS * NNB;      // 368640
constexpr int OFF_LOSS   = OFF_STATS + NPTS * 3;      // 393216 (loss, intra, inter)

// Workspace layout (float offsets)
constexpr int WS_CNORM = 0;            // 8
constexpr int WS_INTER = 8;            // 1
constexpr int WS_XX    = 16;           // 8192 row norms
constexpr int WS_INTRA = 16 + NPTS;    // 512 block partials
constexpr int WS_CAND  = 16 + NPTS + 512; // float2[NPTS][40] candidates (key, idx)
constexpr size_t XB_OFF = 4u << 20;    // byte offset of packed bf16 copy of x (8 MB)

typedef short bf16x8 __attribute__((ext_vector_type(8)));
typedef float f32x16 __attribute__((ext_vector_type(16)));

__device__ __forceinline__ float waveAllSum(float v) {
#pragma unroll
  for (int m = 1; m < 64; m <<= 1) v += __shfl_xor(v, m);
  return v;
}
__device__ __forceinline__ float waveAllMax(float v) {
#pragma unroll
  for (int m = 1; m < 64; m <<= 1) v = fmaxf(v, __shfl_xor(v, m));
  return v;
}

__device__ __forceinline__ unsigned short f2bf(float f) {
  unsigned u = __float_as_uint(f);
  unsigned r = (u + 0x7FFFu + ((u >> 16) & 1u)) >> 16;  // RNE
  return (unsigned short)r;
}

// async global(16B/lane) -> LDS, linear dest (wave-uniform base + lane*16)
__device__ __forceinline__ void gload16(const void* g, void* lds) {
  __builtin_amdgcn_global_load_lds(
      (const __attribute__((address_space(1))) unsigned int*)(unsigned long long)g,
      (__attribute__((address_space(3))) unsigned int*)(unsigned)(unsigned long long)lds,
      16, 0, 0);
}

// ---------------- k_init: center norms + inter-cluster distance ----------------
__global__ void k_init(const float* __restrict__ cc, float* __restrict__ ws) {
  int t = threadIdx.x;
  if (t < KC) {
    float s = 0.f;
    for (int j = 0; j < DIM; j++) { float v = cc[t * DIM + j]; s = fmaf(v, v, s); }
    ws[WS_CNORM + t] = s;
  }
  __syncthreads();
  int i = t >> 3, j = t & 7;
  float dot = 0.f;
  for (int u = 0; u < DIM; u++) dot = fmaf(cc[i * DIM + u], cc[j * DIM + u], dot);
  float d2 = ws[WS_CNORM + i] + ws[WS_CNORM + j] - 2.f * dot;
  float d = d2 > 0.f ? sqrtf(d2) : 0.f;
  float v = (i != j) ? d : 0.f;
  v = waveAllSum(v);
  if (t == 0) ws[WS_INTER] = v / 56.f;
}

// ---------------- k_stats: row stats + soft assignment + intra partials --------
__global__ __launch_bounds__(256) void k_stats(
    const float* __restrict__ x, const float* __restrict__ cc,
    const float* __restrict__ temp, const float* __restrict__ cw,
    float* __restrict__ out, float* __restrict__ ws) {
  __shared__ __align__(16) float Cs[KC * DIM];
  __shared__ float cns[KC], cwS[KC];
  __shared__ float intraS[4];
  int tid = threadIdx.x;
  for (int i = tid * 4; i < KC * DIM; i += 1024)
    *(float4*)&Cs[i] = *(const float4*)&cc[i];
  if (tid < KC) { cns[tid] = ws[WS_CNORM + tid]; cwS[tid] = cw[tid]; }
  __syncthreads();
  float T = temp[0];
  int w = tid >> 6, l = tid & 63;
  float intra_acc = 0.f;
  for (int q = 0; q < 4; q++) {
    int row = blockIdx.x * 16 + w * 4 + q;
    float4 v0 = *(const float4*)&x[row * DIM + l * 4];
    float4 v1 = *(const float4*)&x[row * DIM + 256 + l * 4];
    float xv[8] = {v0.x, v0.y, v0.z, v0.w, v1.x, v1.y, v1.z, v1.w};
    float s1 = 0.f, s2 = 0.f, mx = -3e38f;
#pragma unroll
    for (int u = 0; u < 8; u++) { s1 += xv[u]; s2 = fmaf(xv[u], xv[u], s2); mx = fmaxf(mx, xv[u]); }
    s1 = waveAllSum(s1); s2 = waveAllSum(s2); mx = waveAllMax(mx);
    float e = 0.f, ex = 0.f;
#pragma unroll
    for (int u = 0; u < 8; u++) { float p = expf(xv[u] - mx); e += p; ex = fmaf(xv[u], p, ex); }
    e = waveAllSum(e); ex = waveAllSum(ex);
    float dk[KC];
#pragma unroll
    for (int k = 0; k < KC; k++) {
      float4 c0 = *(const float4*)&Cs[k * DIM + l * 4];
      float4 c1 = *(const float4*)&Cs[k * DIM + 256 + l * 4];
      float d = v0.x * c0.x + v0.y * c0.y + v0.z * c0.z + v0.w * c0.w
              + v1.x * c1.x + v1.y * c1.y + v1.z * c1.z + v1.w * c1.w;
      dk[k] = waveAllSum(d);
    }
    float mu = s1 / 512.f;
    float var = (s2 - 512.f * mu * mu) / 511.f;
    if (var < 0.f) var = 0.f;
    float sd = sqrtf(var) + 1e-8f;
    float lse = mx + logf(e);
    float ent = lse - ex / e;
    float dcv[KC], am = -3e38f;
#pragma unroll
    for (int k = 0; k < KC; k++) {
      float d2 = s2 + cns[k] - 2.f * dk[k];
      dcv[k] = d2 > 0.f ? sqrtf(d2) : 0.f;
      am = fmaxf(am, -dcv[k] / T);
    }
    float psum = 0.f, pv[KC];
#pragma unroll
    for (int k = 0; k < KC; k++) { pv[k] = expf(-dcv[k] / T - am); psum += pv[k]; }
    float il = 0.f, asg[KC];
#pragma unroll
    for (int k = 0; k < KC; k++) { asg[k] = pv[k] / psum * cwS[k]; il = fmaf(dcv[k], asg[k], il); }
    intra_acc += il;
    if (l == 0) {
      ws[WS_XX + row] = s2;
      out[OFF_STATS + row * 3 + 0] = mu;
      out[OFF_STATS + row * 3 + 1] = sd;
      out[OFF_STATS + row * 3 + 2] = ent;
#pragma unroll
      for (int k = 0; k < KC; k++) out[OFF_ASSIGN + row * KC + k] = asg[k];
    }
  }
  if (l == 0) intraS[w] = intra_acc;
  __syncthreads();
  if (tid == 0)
    ws[WS_INTRA + blockIdx.x] = intraS[0] + intraS[1] + intraS[2] + intraS[3];
}

// ---------------- k_final: scalar loss outputs ----------------
__global__ void k_final(float* __restrict__ out, const float* __restrict__ ws) {
  __shared__ float ps[4];
  int t = threadIdx.x;
  float v = ws[WS_INTRA + t] + ws[WS_INTRA + t + 256];
  v = waveAllSum(v);
  if ((t & 63) == 0) ps[t >> 6] = v;
  __syncthreads();
  if (t == 0) {
    float intra = (ps[0] + ps[1] + ps[2] + ps[3]) / (8192.f * 8.f);
    float inter = ws[WS_INTER];
    out[OFF_LOSS + 0] = intra - 0.1f * inter;
    out[OFF_LOSS + 1] = intra;
    out[OFF_LOSS + 2] = inter;
  }
}

// ---------------- k_pack: x f32 -> bf16 packed into MFMA fragment layout ------
// Unit = (grp = point>>5, kk = k>>4): 64 lanes x 16B; lane = (point&31) + 32*((k>>3)&1),
// lane bytes = bf16 of k in [kk*16 + (lane>>5)*8, +8). Flat: xp[((grp*32+kk)*64+lane)*8 ushorts]
__global__ __launch_bounds__(256) void k_pack(const float* __restrict__ x,
                                              unsigned short* __restrict__ xp) {
  int t = blockIdx.x * 256 + threadIdx.x;   // one thread per 16B unit-lane
  int lane = t & 63;
  int kk = (t >> 6) & 31;
  int grp = t >> 11;
  int point = grp * 32 + (lane & 31);
  int k0 = kk * 16 + (lane >> 5) * 8;
  const float* src = x + point * DIM + k0;
  float4 v0 = *(const float4*)src;
  float4 v1 = *(const float4*)(src + 4);
  bf16x8 o;
  o[0] = (short)f2bf(v0.x); o[1] = (short)f2bf(v0.y);
  o[2] = (short)f2bf(v0.z); o[3] = (short)f2bf(v0.w);
  o[4] = (short)f2bf(v1.x); o[5] = (short)f2bf(v1.y);
  o[6] = (short)f2bf(v1.z); o[7] = (short)f2bf(v1.w);
  *(bf16x8*)(xp + (size_t)t * 8) = o;
}

// ---------------- k_gemm3: barrier-free MFMA distances + fused noisy top-5 ----
// grid (128, 4) XCD-swizzled; block = 512 threads (8 waves), 64 rows x 2048 cols.
// Rows (64x512 bf16 = 64KB) staged ONCE in LDS via gload16 (packed layout = linear).
// Cols stream global->VGPR (packed, coalesced 16B/lane). No K-loop barriers.
// Swapped operands: acc = mfma(colfrag, rowfrag) -> row in lane, 16 cols in regs.

#define INS5(P, KEY, IDX)                                                        \
  { float a_ = (KEY); int b_ = (IDX);                                            \
    if (a_ < k##P##0) { float t_=k##P##0; k##P##0=a_; a_=t_; int u_=i##P##0; i##P##0=b_; b_=u_; } \
    if (a_ < k##P##1) { float t_=k##P##1; k##P##1=a_; a_=t_; int u_=i##P##1; i##P##1=b_; b_=u_; } \
    if (a_ < k##P##2) { float t_=k##P##2; k##P##2=a_; a_=t_; int u_=i##P##2; i##P##2=b_; b_=u_; } \
    if (a_ < k##P##3) { float t_=k##P##3; k##P##3=a_; a_=t_; int u_=i##P##3; i##P##3=b_; b_=u_; } \
    if (a_ < k##P##4) { float t_=k##P##4; k##P##4=a_; a_=t_; int u_=i##P##4; i##P##4=b_; b_=u_; } \
    float t5_ = k##P##4 + 8e-6f; t2##P = t5_ * t5_; }

#define PROC(P, DOT, XC, COL, ROW, XR, NROW)                                     \
  { float d2_ = (XR) + (XC) - 2.0f * (DOT);                                      \
    if (d2_ < t2##P) {                                                           \
      float d_ = sqrtf(fmaxf(d2_, 0.0f));                                        \
      int c_ = (COL);                                                            \
      if (c_ != (ROW)) {                                                         \
        float key_ = fmaf(1e-6f, (NROW)[c_], d_);                                \
        if (key_ < k##P##4) { INS5(P, key_, c_) }                                \
      } } }

__global__ __launch_bounds__(512, 4) void k_gemm3(
    const unsigned short* __restrict__ xp, const float* __restrict__ noise,
    float* __restrict__ ws) {
  __shared__ __align__(16) char SMEM[65536];
  const int tid = threadIdx.x;
  const int l = tid & 63, w = tid >> 6;
  const int lh = l >> 5;

  // XCD-chunked swizzle: each XCD owns a contiguous range of work ids -> one
  // col-chunk pair stays hot in its L2 (2 MB col working set < 4 MB L2/XCD).
  const int flat = blockIdx.y * 128 + blockIdx.x;
  const int work = (flat & 7) * 64 + (flat >> 3);
  const int rb = work & 127;          // row-block (64 rows)
  const int cchunk = work >> 7;       // col chunk (2048 cols)
  const int rowbase = rb * 64;
  const int colbase = cchunk * 2048;

  const float* xxg = ws + WS_XX;
  float2* candp = (float2*)(ws + WS_CAND);

  // ---- stage 64 rows x 512 k once: 64 x 1KB units, wave w stages units w*8..w*8+7
  {
    const int rg0 = rb * 2;
#pragma unroll
    for (int i = 0; i < 8; i++) {
      const int u = w * 8 + i;                              // u = g*32 + kk
      const size_t src = ((size_t)(rg0 + (u >> 5)) * 32 + (u & 31)) * 512 + l * 8;
      gload16(xp + src, SMEM + u * 1024);
    }
  }

  const int rowA = rowbase + (l & 31);
  const int rowB = rowA + 32;
  const float xxrA = xxg[rowA], xxrB = xxg[rowB];
  const float* nrowA = noise + (size_t)rowA * NPTS;
  const float* nrowB = noise + (size_t)rowB * NPTS;

  float ka0=3e38f,ka1=3e38f,ka2=3e38f,ka3=3e38f,ka4=3e38f;
  float kb0=3e38f,kb1=3e38f,kb2=3e38f,kb3=3e38f,kb4=3e38f;
  int   ia0=-1,ia1=-1,ia2=-1,ia3=-1,ia4=-1;
  int   ib0=-1,ib1=-1,ib2=-1,ib3=-1,ib4=-1;
  float t2a = 3e38f, t2b = 3e38f;

  __syncthreads();  // rows resident; ONLY barrier before the merge phase

  for (int ct = 0; ct < 8; ct++) {
    const int cgrp = cchunk * 64 + ct * 8 + w;     // this wave's 32-col group
    const unsigned short* colp = xp + (size_t)cgrp * 16384 + l * 8;

    f32x16 a0, a1;
#pragma unroll
    for (int r = 0; r < 16; r++) { a0[r] = 0.f; a1[r] = 0.f; }

#pragma unroll 2
    for (int kk = 0; kk < 32; kk++) {
      bf16x8 cf = *(const bf16x8*)(colp + kk * 512);
      const char* rp = SMEM + kk * 1024 + l * 16;
      bf16x8 r0 = *(const bf16x8*)rp;
      bf16x8 r1 = *(const bf16x8*)(rp + 32768);
      a0 = __builtin_amdgcn_mfma_f32_32x32x16_bf16(cf, r0, a0, 0, 0, 0);
      a1 = __builtin_amdgcn_mfma_f32_32x32x16_bf16(cf, r1, a1, 0, 0, 0);
    }

    // epilogue: lane-local top-5 over 2 rows x 16 cols
    const int colt = colbase + ct * 256 + w * 32;
    float xq[16];
#pragma unroll
    for (int g = 0; g < 4; g++) {
      float4 t0 = *(const float4*)&xxg[colt + 8 * g + 4 * lh];
      xq[4*g+0]=t0.x; xq[4*g+1]=t0.y; xq[4*g+2]=t0.z; xq[4*g+3]=t0.w;
    }
#pragma unroll
    for (int r = 0; r < 16; r++) {
      const int cOff = (r & 3) + 8 * (r >> 2) + 4 * lh;
      PROC(a, a0[r], xq[r], colt + cOff, rowA, xxrA, nrowA)
      PROC(b, a1[r], xq[r], colt + cOff, rowB, xxrB, nrowB)
    }
  }

  // ---- lane^32 merge (lanes l, l^32 share the same two rows) ----
  float MA[5], MB_[5]; int JA[5], JB_[5];
  {
    float m0=ka0,m1=ka1,m2=ka2,m3=ka3,m4=ka4;
    int   n0=ia0,n1=ia1,n2=ia2,n3=ia3,n4=ia4;
#pragma unroll
    for (int s = 0; s < 5; s++) {
      float ok = __shfl_xor(m0, 32); int oi = __shfl_xor(n0, 32);
      bool take = (m0 < ok) || (m0 == ok && (unsigned)n0 <= (unsigned)oi);
      MA[s] = take ? m0 : ok; JA[s] = take ? n0 : oi;
      if (take) { m0=m1;n0=n1; m1=m2;n1=n2; m2=m3;n2=n3; m3=m4;n3=n4; m4=3e38f;n4=-1; }
    }
  }
  {
    float m0=kb0,m1=kb1,m2=kb2,m3=kb3,m4=kb4;
    int   n0=ib0,n1=ib1,n2=ib2,n3=ib3,n4=ib4;
#pragma unroll
    for (int s = 0; s < 5; s++) {
      float ok = __shfl_xor(m0, 32); int oi = __shfl_xor(n0, 32);
      bool take = (m0 < ok) || (m0 == ok && (unsigned)n0 <= (unsigned)oi);
      MB_[s] = take ? m0 : ok; JB_[s] = take ? n0 : oi;
      if (take) { m0=m1;n0=n1; m1=m2;n1=n2; m2=m3;n2=n3; m3=m4;n3=n4; m4=3e38f;n4=-1; }
    }
  }

  // ---- cross-wave merge: lane l owns row l; 8 waves' lists via LDS ----
  __syncthreads();  // done reading row tile
  float2* mrg = (float2*)SMEM;  // [64 rows][8 waves][5]
#pragma unroll
  for (int s = 0; s < 5; s++) {
    float2 e = (l < 32) ? make_float2(MA[s], __int_as_float(JA[s]))
                        : make_float2(MB_[s], __int_as_float(JB_[s]));
    mrg[(l * 8 + w) * 5 + s] = e;
  }
  __syncthreads();
  if (l < 8) {
    const int row = w * 8 + l;   // 8 waves x 8 lanes cover 64 rows
    float2 h[8]; int p[8];
#pragma unroll
    for (int j = 0; j < 8; j++) { h[j] = mrg[(row * 8 + j) * 5]; p[j] = 0; }
    const size_t base = (size_t)(rowbase + row) * 40 + cchunk * 5;
#pragma unroll
    for (int s = 0; s < 5; s++) {
      int bj = 0; float bk = h[0].x; int bi = __float_as_int(h[0].y);
#pragma unroll
      for (int j = 1; j < 8; j++) {
        float kj = h[j].x; int ij = __float_as_int(h[j].y);
        if (kj < bk || (kj == bk && (unsigned)ij < (unsigned)bi)) { bk = kj; bi = ij; bj = j; }
      }
      candp[base + s] = make_float2(bk, __int_as_float(bi));
      p[bj]++;
      h[bj] = (p[bj] < 5) ? mrg[(row * 8 + bj) * 5 + p[bj]]
                          : make_float2(3e38f, __int_as_float(-1));
    }
  }
}

// ---------------- k_gemm (fallback, fp32 VALU): unchanged ----------------
__global__ __launch_bounds__(256, 2) void k_gemm(
    const float* __restrict__ x, const float* __restrict__ noise,
    float* __restrict__ ws) {
  __shared__ __align__(16) float As[16][132];
  __shared__ __align__(16) float Bs[16][132];
  __shared__ float xxc[1024];
  const int tid = threadIdx.x;
  const int tx = tid & 7, ty = tid >> 3;
  const int rowbase = blockIdx.x * 128;
  const int colbase = blockIdx.y * 1024;
  const float* xxg = ws + WS_XX;

  for (int i = tid; i < 1024; i += 256) xxc[i] = xxg[colbase + i];
  float xxr[4];
#pragma unroll
  for (int r = 0; r < 4; r++) xxr[r] = xxg[rowbase + ty * 4 + r];

  float k5[4][5]; int i5[4][5];
#pragma unroll
  for (int r = 0; r < 4; r++)
#pragma unroll
    for (int s = 0; s < 5; s++) { k5[r][s] = 3e38f; i5[r][s] = -1; }

  const int rlo = tid >> 2, kq = tid & 3;

  for (int ct = 0; ct < 8; ct++) {
    const int colt = colbase + ct * 128;
    float acc[4][16];
#pragma unroll
    for (int r = 0; r < 4; r++)
#pragma unroll
      for (int c = 0; c < 16; c++) acc[r][c] = 0.f;

    for (int kk = 0; kk < 512; kk += 16) {
      __syncthreads();
      float4 a0 = *(const float4*)&x[(rowbase + rlo) * DIM + kk + kq * 4];
      float4 a1 = *(const float4*)&x[(rowbase + rlo + 64) * DIM + kk + kq * 4];
      float4 b0 = *(const float4*)&x[(colt + rlo) * DIM + kk + kq * 4];
      float4 b1 = *(const float4*)&x[(colt + rlo + 64) * DIM + kk + kq * 4];
      As[kq * 4 + 0][rlo] = a0.x; As[kq * 4 + 1][rlo] = a0.y;
      As[kq * 4 + 2][rlo] = a0.z; As[kq * 4 + 3][rlo] = a0.w;
      As[kq * 4 + 0][rlo + 64] = a1.x; As[kq * 4 + 1][rlo + 64] = a1.y;
      As[kq * 4 + 2][rlo + 64] = a1.z; As[kq * 4 + 3][rlo + 64] = a1.w;
      Bs[kq * 4 + 0][rlo] = b0.x; Bs[kq * 4 + 1][rlo] = b0.y;
      Bs[kq * 4 + 2][rlo] = b0.z; Bs[kq * 4 + 3][rlo] = b0.w;
      Bs[kq * 4 + 0][rlo + 64] = b1.x; Bs[kq * 4 + 1][rlo + 64] = b1.y;
      Bs[kq * 4 + 2][rlo + 64] = b1.z; Bs[kq * 4 + 3][rlo + 64] = b1.w;
      __syncthreads();
#pragma unroll
      for (int k = 0; k < 16; k++) {
        float4 av = *(const float4*)&As[k][ty * 4];
        float a_[4] = {av.x, av.y, av.z, av.w};
#pragma unroll
        for (int j = 0; j < 4; j++) {
          float4 bv = *(const float4*)&Bs[k][tx * 4 + j * 32];
          float b_[4] = {bv.x, bv.y, bv.z, bv.w};
#pragma unroll
          for (int rr = 0; rr < 4; rr++)
#pragma unroll
            for (int uu = 0; uu < 4; uu++)
              acc[rr][j * 4 + uu] = fmaf(a_[rr], b_[uu], acc[rr][j * 4 + uu]);
        }
      }
    }
#pragma unroll
    for (int r = 0; r < 4; r++) {
      const int row = rowbase + ty * 4 + r;
#pragma unroll
      for (int j = 0; j < 4; j++) {
        const int cl = tx * 4 + j * 32;
        const int col = colt + cl;
        const float4 nz = *(const float4*)&noise[(size_t)row * NPTS + col];
        float nzv[4] = {nz.x, nz.y, nz.z, nz.w};
#pragma unroll
        for (int u = 0; u < 4; u++) {
          float d2 = xxr[r] + xxc[ct * 128 + cl + u] - 2.f * acc[r][j * 4 + u];
          float d = d2 > 0.f ? sqrtf(d2) : 0.f;
          float key = d + 1e-6f * nzv[u];
          int c = col + u;
          if (c != row && key < k5[r][4]) {
            float a = key; int b = c;
#pragma unroll
            for (int s = 0; s < 5; s++) {
              if (a < k5[r][s]) {
                float tf = k5[r][s]; k5[r][s] = a; a = tf;
                int ti = i5[r][s]; i5[r][s] = b; b = ti;
              }
            }
          }
        }
      }
    }
  }

#pragma unroll
  for (int r = 0; r < 4; r++) {
    const int row = rowbase + ty * 4 + r;
    float lk[5]; int li[5];
#pragma unroll
    for (int s = 0; s < 5; s++) { lk[s] = k5[r][s]; li[s] = i5[r][s]; }
#pragma unroll
    for (int s = 0; s < 5; s++) {
      float wk = lk[0]; int wi = li[0];
#pragma unroll
      for (int m = 1; m < 8; m <<= 1) {
        float k2 = __shfl_xor(wk, m); int i2 = __shfl_xor(wi, m);
        if (k2 < wk || (k2 == wk && (unsigned)i2 < (unsigned)wi)) { wk = k2; wi = i2; }
      }
      if (li[0] == wi && lk[0] == wk) {
        lk[0] = lk[1]; li[0] = li[1];
        lk[1] = lk[2]; li[1] = li[2];
        lk[2] = lk[3]; li[2] = li[3];
        lk[3] = lk[4]; li[3] = li[4];
        lk[4] = 3e38f; li[4] = -1;
      }
      if (tx == 0) {
        float2* cand = (float2*)(ws + WS_CAND);
        cand[(size_t)row * 40 + blockIdx.y * 5 + s] = make_float2(wk, __int_as_float(wi));
      }
    }
  }
}

// ---------------- k_merge: final top-5 + feats + MLP ----------------
__global__ __launch_bounds__(256) void k_merge(
    const float* __restrict__ noise, const float* __restrict__ w1,
    const float* __restrict__ b1, const float* __restrict__ w2,
    const float* __restrict__ b2, float* __restrict__ out,
    const float* __restrict__ ws, int nslots) {
  __shared__ float w1s[16 * 64];
  __shared__ float b1s[64];
  __shared__ float w2s[64 * 32];
  __shared__ float b2s[32];
  __shared__ float featsS[4][16];
  __shared__ float hS[4][64];
  int tid = threadIdx.x;
  for (int i = tid; i < 1024; i += 256) w1s[i] = w1[i];
  for (int i = tid; i < 2048; i += 256) w2s[i] = w2[i];
  if (tid < 64) b1s[tid] = b1[tid];
  if (tid < 32) b2s[tid] = b2[tid];
  __syncthreads();
  int w = tid >> 6, l = tid & 63;
  const float2* cand = (const float2*)(ws + WS_CAND);
  for (int q = 0; q < 8; q++) {
    int row = blockIdx.x * 32 + w * 8 + q;
    float mk = 3e38f; int mi = -1;
    if (l < nslots) {
      float2 c = cand[(size_t)row * 40 + l];
      mk = c.x; mi = __float_as_int(c.y);
    }
#pragma unroll
    for (int s = 0; s < 5; s++) {
      float wk = mk; int wi = mi;
#pragma unroll
      for (int m = 1; m < 64; m <<= 1) {
        float k2 = __shfl_xor(wk, m); int i2 = __shfl_xor(wi, m);
        if (k2 < wk || (k2 == wk && (unsigned)i2 < (unsigned)wi)) { wk = k2; wi = i2; }
      }
      if (mi == wi && mk == wk) mk = 3e38f;  // remove winner from my slot
      if (l == s) {
        float nv = noise[(size_t)row * NPTS + wi];
        float dclean = wk - 1e-6f * nv;
        out[OFF_KNN + row * NNB + s] = dclean;
        featsS[w][8 + s] = dclean;
      }
    }
    if (l < 8) featsS[w][l] = out[OFF_ASSIGN + row * KC + l];
    if (l >= 13 && l < 16) featsS[w][l] = out[OFF_STATS + row * 3 + (l - 13)];
    __syncthreads();
    float h = b1s[l];
#pragma unroll
    for (int i = 0; i < 16; i++) h = fmaf(featsS[w][i], w1s[i * 64 + l], h);
    hS[w][l] = fmaxf(h, 0.f);
    __syncthreads();
    if (l < 32) {
      float e = b2s[l];
#pragma unroll
      for (int i = 0; i < 64; i++) e = fmaf(hS[w][i], w2s[i * 32 + l], e);
      out[OFF_ENC + row * 32 + l] = e;
    }
    __syncthreads();
  }
}

extern "C" void kernel_launch(void* const* d_in, const int* in_sizes, int n_in,
                              void* d_out, int out_size, void* d_ws, size_t ws_size,
                              hipStream_t stream) {
  const float* x     = (const float*)d_in[0];
  const float* noise = (const float*)d_in[1];
  const float* cc    = (const float*)d_in[2];
  const float* w1    = (const float*)d_in[3];
  const float* b1    = (const float*)d_in[4];
  const float* w2    = (const float*)d_in[5];
  const float* b2    = (const float*)d_in[6];
  const float* temp  = (const float*)d_in[7];
  const float* cw    = (const float*)d_in[8];
  float* out = (float*)d_out;
  float* ws  = (float*)d_ws;

  const size_t need = XB_OFF + (size_t)NPTS * DIM * 2;  // 12.4 MB
  const bool fast = ws_size >= need;

  hipLaunchKernelGGL(k_init,  dim3(1),   dim3(64),  0, stream, cc, ws);
  hipLaunchKernelGGL(k_stats, dim3(512), dim3(256), 0, stream, x, cc, temp, cw, out, ws);
  hipLaunchKernelGGL(k_final, dim3(1),   dim3(256), 0, stream, out, ws);
  if (fast) {
    unsigned short* xp = (unsigned short*)((char*)d_ws + XB_OFF);
    hipLaunchKernelGGL(k_pack,  dim3(2048),  dim3(256), 0, stream, x, xp);
    hipLaunchKernelGGL(k_gemm3, dim3(128, 4), dim3(512), 0, stream, xp, noise, ws);
    hipLaunchKernelGGL(k_merge, dim3(256), dim3(256), 0, stream, noise, w1, b1, w2, b2, out, ws, 20);
  } else {
    hipLaunchKernelGGL(k_gemm,  dim3(64, 8), dim3(256), 0, stream, x, noise, ws);
    hipLaunchKernelGGL(k_merge, dim3(256), dim3(256), 0, stream, noise, w1, b1, w2, b2, out, ws, 40);
  }
}